// Round 1
// baseline (2422.348 us; speedup 1.0000x reference)
//
#include <hip/hip_runtime.h>
#include <math.h>

#define NBATCH 1024
#define LATD 64
#define HIDD 128
#define NOISED 16
#define OUTD 32
#define INOISED 64
#define TT 128
#define NB 4   // batch rows per block

// ws layout (float offsets)
#define OFF_DW1T 0        // [65][128]
#define OFF_DW2T 8320     // [128][128]
#define OFF_DW3T 24704    // [128][64]
#define OFF_GW1T 32896    // [65][128]
#define OFF_GW2T 41216    // [128][128]
#define OFF_GW3T 57600    // [128][1024]
#define OFF_EMBT 188672   // [64][64]
#define OFF_RO1T 192768   // [64][128]
#define OFF_RO2T 200960   // [128][32]

__device__ __forceinline__ float lipswish(float x) {
  return 0.909f * x / (1.0f + expf(-x));
}

// ---------------- prep: weight-norm + transpose into ws ----------------
__global__ void prep_kernel(const float* dr_v1, const float* dr_g1,
                            const float* dr_v2, const float* dr_g2,
                            const float* dr_v3, const float* dr_g3,
                            const float* di_v1, const float* di_g1,
                            const float* di_v2, const float* di_g2,
                            const float* di_v3, const float* di_g3,
                            const float* emb_W, const float* ro_W1, const float* ro_W2,
                            float* ws) {
  __shared__ float sred[2];
  const int mat = blockIdx.y;
  const int row = blockIdx.x;
  const int i = threadIdx.x;
  const float* v = nullptr; const float* g = nullptr; float* outp = nullptr;
  int rows = 0, len = 0, ldo = 0;
  switch (mat) {
    case 0: v = dr_v1; g = dr_g1; outp = ws + OFF_DW1T; rows = 128;  len = 65;  ldo = 128;  break;
    case 1: v = dr_v2; g = dr_g2; outp = ws + OFF_DW2T; rows = 128;  len = 128; ldo = 128;  break;
    case 2: v = dr_v3; g = dr_g3; outp = ws + OFF_DW3T; rows = 64;   len = 128; ldo = 64;   break;
    case 3: v = di_v1; g = di_g1; outp = ws + OFF_GW1T; rows = 128;  len = 65;  ldo = 128;  break;
    case 4: v = di_v2; g = di_g2; outp = ws + OFF_GW2T; rows = 128;  len = 128; ldo = 128;  break;
    case 5: v = di_v3; g = di_g3; outp = ws + OFF_GW3T; rows = 1024; len = 128; ldo = 1024; break;
    case 6: v = emb_W; g = nullptr; outp = ws + OFF_EMBT; rows = 64;  len = 64;  ldo = 64;  break;
    case 7: v = ro_W1; g = nullptr; outp = ws + OFF_RO1T; rows = 128; len = 64;  ldo = 128; break;
    case 8: v = ro_W2; g = nullptr; outp = ws + OFF_RO2T; rows = 32;  len = 128; ldo = 32;  break;
  }
  if (row >= rows) return;
  const float x = (i < len) ? v[(size_t)row * len + i] : 0.0f;
  float scale = 1.0f;
  if (g != nullptr) {
    float ss = x * x;
    #pragma unroll
    for (int d = 1; d < 64; d <<= 1) ss += __shfl_xor(ss, d);
    if ((threadIdx.x & 63) == 0) sred[threadIdx.x >> 6] = ss;
    __syncthreads();
    const float tot = sred[0] + sred[1];
    scale = g[row] / sqrtf(tot);
  }
  if (i < len) outp[(size_t)i * ldo + row] = x * scale;
}

// 4-row partial-dot macro: accumulators a0..a3 must exist; WP advances.
#define DOT4ROWS(NI4, P0, P1, P2, P3, WP, WS) \
  _Pragma("unroll") \
  for (int i4_ = 0; i4_ < (NI4); ++i4_) { \
    const float4 v0_ = (P0)[i4_], v1_ = (P1)[i4_], v2_ = (P2)[i4_], v3_ = (P3)[i4_]; \
    const float w0_ = (WP)[0], w1_ = (WP)[(WS)], w2_ = (WP)[2 * (WS)], w3_ = (WP)[3 * (WS)]; \
    (WP) += 4 * (WS); \
    a0 = fmaf(v0_.x, w0_, a0); a1 = fmaf(v1_.x, w0_, a1); a2 = fmaf(v2_.x, w0_, a2); a3 = fmaf(v3_.x, w0_, a3); \
    a0 = fmaf(v0_.y, w1_, a0); a1 = fmaf(v1_.y, w1_, a1); a2 = fmaf(v2_.y, w1_, a2); a3 = fmaf(v3_.y, w1_, a3); \
    a0 = fmaf(v0_.z, w2_, a0); a1 = fmaf(v1_.z, w2_, a1); a2 = fmaf(v2_.z, w2_, a2); a3 = fmaf(v3_.z, w2_, a3); \
    a0 = fmaf(v0_.w, w3_, a0); a1 = fmaf(v1_.w, w3_, a1); a2 = fmaf(v2_.w, w3_, a2); a3 = fmaf(v3_.w, w3_, a3); \
  }

// layer1: input = [t, z(64)], 128 outs, 2-way i-split. part[(ih*NB+r)*HIDD+o]
__device__ __forceinline__ void l1_partial(int t, float tval, const float (*zb)[LATD],
                                           const float* __restrict__ Wt,
                                           float* __restrict__ part) {
  const int ih = t >> 7;
  const int o = t & 127;
  float a0 = 0.f, a1 = 0.f, a2 = 0.f, a3 = 0.f;
  const float* wp;
  if (ih == 0) {
    const float w = Wt[o];
    a0 = w * tval; a1 = a0; a2 = a0; a3 = a0;
    wp = Wt + HIDD + o;           // z rows 0..31 (weight rows 1..32)
  } else {
    wp = Wt + 33 * HIDD + o;      // z rows 32..63 (weight rows 33..64)
  }
  const float4* p0 = (const float4*)zb[0] + ih * 8;
  const float4* p1 = (const float4*)zb[1] + ih * 8;
  const float4* p2 = (const float4*)zb[2] + ih * 8;
  const float4* p3 = (const float4*)zb[3] + ih * 8;
  DOT4ROWS(8, p0, p1, p2, p3, wp, HIDD)
  float* pb = part + (ih * NB) * HIDD + o;
  pb[0] = a0; pb[HIDD] = a1; pb[2 * HIDD] = a2; pb[3 * HIDD] = a3;
}

// hidden layer: K=128 -> 128 outs, 2-way i-split
__device__ __forceinline__ void hid_partial(int t, const float (*inb)[HIDD],
                                            const float* __restrict__ Wt,
                                            float* __restrict__ part) {
  const int ih = t >> 7;
  const int o = t & 127;
  const float* wp = Wt + ih * 64 * HIDD + o;
  const float4* p0 = (const float4*)inb[0] + ih * 16;
  const float4* p1 = (const float4*)inb[1] + ih * 16;
  const float4* p2 = (const float4*)inb[2] + ih * 16;
  const float4* p3 = (const float4*)inb[3] + ih * 16;
  float a0 = 0.f, a1 = 0.f, a2 = 0.f, a3 = 0.f;
  DOT4ROWS(16, p0, p1, p2, p3, wp, HIDD)
  float* pb = part + (ih * NB) * HIDD + o;
  pb[0] = a0; pb[HIDD] = a1; pb[2 * HIDD] = a2; pb[3 * HIDD] = a3;
}

__device__ __forceinline__ void hid_combine(int t, const float* __restrict__ part,
                                            const float* __restrict__ bias,
                                            float (*outb)[HIDD], bool act) {
  const int r = t >> 6;
  const int o2 = (t & 63) * 2;
  const float x0 = part[r * HIDD + o2]     + part[(NB + r) * HIDD + o2]     + bias[o2];
  const float x1 = part[r * HIDD + o2 + 1] + part[(NB + r) * HIDD + o2 + 1] + bias[o2 + 1];
  outb[r][o2]     = act ? lipswish(x0) : x0;
  outb[r][o2 + 1] = act ? lipswish(x1) : x1;
}

// layer3 (drift): K=128 -> 64 outs, 4-way i-split
__device__ __forceinline__ void l3_partial(int t, const float (*inb)[HIDD],
                                           const float* __restrict__ Wt,
                                           float* __restrict__ part) {
  const int iq = t >> 6;
  const int o = t & 63;
  const float* wp = Wt + iq * 32 * LATD + o;
  const float4* p0 = (const float4*)inb[0] + iq * 8;
  const float4* p1 = (const float4*)inb[1] + iq * 8;
  const float4* p2 = (const float4*)inb[2] + iq * 8;
  const float4* p3 = (const float4*)inb[3] + iq * 8;
  float a0 = 0.f, a1 = 0.f, a2 = 0.f, a3 = 0.f;
  DOT4ROWS(8, p0, p1, p2, p3, wp, LATD)
  float* pb = part + (iq * NB) * LATD + o;
  pb[0] = a0; pb[LATD] = a1; pb[2 * LATD] = a2; pb[3 * LATD] = a3;
}

__device__ __forceinline__ void l3_combine(int t, const float* __restrict__ part,
                                           const float* __restrict__ bias,
                                           float (*outb)[LATD]) {
  const int r = t >> 6;
  const int o = t & 63;
  outb[r][o] = part[r * LATD + o] + part[(NB + r) * LATD + o] +
               part[(2 * NB + r) * LATD + o] + part[(3 * NB + r) * LATD + o] + bias[o];
}

// diffusion L3 (128 -> 1024) fused with dual noise contraction
__device__ __forceinline__ void diff_layer3(int t, const float (*hb)[HIDD],
                                            const float* __restrict__ gW3t,
                                            const float* __restrict__ b3,
                                            const float (*dwi)[NOISED], const float (*dwn)[NOISED],
                                            float (*u1)[LATD], float (*v1)[LATD]) {
  const int l = t >> 2;
  const int q = t & 3;
  const int o4 = l * 16 + q * 4;
  float4 acc0 = {0, 0, 0, 0}, acc1 = {0, 0, 0, 0}, acc2 = {0, 0, 0, 0}, acc3 = {0, 0, 0, 0};
  const float* wp = gW3t + o4;
  #pragma unroll 2
  for (int i4 = 0; i4 < 32; ++i4) {
    const float4 h0 = *((const float4*)hb[0] + i4);
    const float4 h1 = *((const float4*)hb[1] + i4);
    const float4 h2 = *((const float4*)hb[2] + i4);
    const float4 h3 = *((const float4*)hb[3] + i4);
#define DL3S(C) { \
    const float4 w = *(const float4*)wp; wp += NBATCH; \
    acc0.x = fmaf(h0.C, w.x, acc0.x); acc0.y = fmaf(h0.C, w.y, acc0.y); acc0.z = fmaf(h0.C, w.z, acc0.z); acc0.w = fmaf(h0.C, w.w, acc0.w); \
    acc1.x = fmaf(h1.C, w.x, acc1.x); acc1.y = fmaf(h1.C, w.y, acc1.y); acc1.z = fmaf(h1.C, w.z, acc1.z); acc1.w = fmaf(h1.C, w.w, acc1.w); \
    acc2.x = fmaf(h2.C, w.x, acc2.x); acc2.y = fmaf(h2.C, w.y, acc2.y); acc2.z = fmaf(h2.C, w.z, acc2.z); acc2.w = fmaf(h2.C, w.w, acc2.w); \
    acc3.x = fmaf(h3.C, w.x, acc3.x); acc3.y = fmaf(h3.C, w.y, acc3.y); acc3.z = fmaf(h3.C, w.z, acc3.z); acc3.w = fmaf(h3.C, w.w, acc3.w); }
    DL3S(x) DL3S(y) DL3S(z) DL3S(w)
#undef DL3S
  }
  const float4 bv = *(const float4*)(b3 + o4);
#define ROWC(ACC, R) { \
    const float4 di = *(const float4*)(&dwi[R][q * 4]); \
    const float4 dn = *(const float4*)(&dwn[R][q * 4]); \
    const float g0 = ACC.x + bv.x, g1 = ACC.y + bv.y, g2 = ACC.z + bv.z, g3 = ACC.w + bv.w; \
    float u = g0 * di.x + g1 * di.y + g2 * di.z + g3 * di.w; \
    float vv = g0 * dn.x + g1 * dn.y + g2 * dn.z + g3 * dn.w; \
    u += __shfl_xor(u, 1); u += __shfl_xor(u, 2); \
    vv += __shfl_xor(vv, 1); vv += __shfl_xor(vv, 2); \
    if (q == 0) { u1[R][l] = u; v1[R][l] = vv; } }
  ROWC(acc0, 0) ROWC(acc1, 1) ROWC(acc2, 2) ROWC(acc3, 3)
#undef ROWC
}

// readout stage 1: y(64) -> h(128), 2-way i-split (reuses hid part/combine layout)
__device__ __forceinline__ void ro1_partial(int t, const float (*yb)[LATD],
                                            const float* __restrict__ Wt,
                                            float* __restrict__ part) {
  const int ih = t >> 7;
  const int o = t & 127;
  const float* wp = Wt + ih * 32 * HIDD + o;
  const float4* p0 = (const float4*)yb[0] + ih * 8;
  const float4* p1 = (const float4*)yb[1] + ih * 8;
  const float4* p2 = (const float4*)yb[2] + ih * 8;
  const float4* p3 = (const float4*)yb[3] + ih * 8;
  float a0 = 0.f, a1 = 0.f, a2 = 0.f, a3 = 0.f;
  DOT4ROWS(8, p0, p1, p2, p3, wp, HIDD)
  float* pb = part + (ih * NB) * HIDD + o;
  pb[0] = a0; pb[HIDD] = a1; pb[2 * HIDD] = a2; pb[3 * HIDD] = a3;
}

// readout stage 2 partial: h(128) -> 32 outs, 2-way i-split
__device__ __forceinline__ void ro2_partial(int t, const float (*hb)[HIDD],
                                            const float* __restrict__ Wt,
                                            float* __restrict__ part) {
  const int ih = t >> 7;
  const int r = (t >> 5) & 3;
  const int o = t & 31;
  const float* wp = Wt + ih * 64 * OUTD + o;
  const float4* hp = (const float4*)hb[r] + ih * 16;
  float a = 0.f;
  #pragma unroll
  for (int i4 = 0; i4 < 16; ++i4) {
    const float4 h = hp[i4];
    a = fmaf(h.x, wp[0], a);
    a = fmaf(h.y, wp[OUTD], a);
    a = fmaf(h.z, wp[2 * OUTD], a);
    a = fmaf(h.w, wp[3 * OUTD], a);
    wp += 4 * OUTD;
  }
  part[(ih * NB + r) * OUTD + o] = a;
}

__device__ __forceinline__ void ro2_final(int t, const float* __restrict__ part,
                                          const float* __restrict__ rb2,
                                          float* __restrict__ out,
                                          int b0, int tidx, int steps, int mult) {
  if (t < 128) {
    const int r = t >> 5;
    const int o = t & 31;
    const float a = part[r * OUTD + o] + part[(NB + r) * OUTD + o] + rb2[o];
    const int b = b0 + r;
    out[((size_t)b * TT + tidx) * OUTD + o] = a;
    if (mult > 0 && (tidx % mult) == 0) {
      const int j = tidx / mult;
      if (j < steps)
        out[(size_t)NBATCH * TT * OUTD + ((size_t)b * steps + j) * OUTD + o] = a;
    }
  }
}

__global__ void __launch_bounds__(256)
sde_main(const float* __restrict__ init_noise, const float* __restrict__ bm,
         const float* __restrict__ ts_g, const int* __restrict__ p_steps,
         const int* __restrict__ p_mult,
         const float* __restrict__ emb_b,
         const float* __restrict__ dr_b1, const float* __restrict__ dr_b2, const float* __restrict__ dr_b3,
         const float* __restrict__ di_b1, const float* __restrict__ di_b2, const float* __restrict__ di_b3,
         const float* __restrict__ ro_b1, const float* __restrict__ ro_b2,
         const float* __restrict__ ws, float* __restrict__ out) {
  __shared__ __align__(16) float s_ts[TT];
  __shared__ __align__(16) float s_y[NB][LATD], s_z[NB][LATD], s_f[NB][LATD], s_v[NB][LATD];
  __shared__ __align__(16) float s_f1[NB][LATD], s_u1[NB][LATD], s_v1[NB][LATD];
  __shared__ __align__(16) float s_h1[NB][HIDD], s_h2[NB][HIDD];
  __shared__ __align__(16) float s_dwi[NB][NOISED], s_dwn[NB][NOISED];
  __shared__ __align__(16) float s_part[2 * NB * HIDD];  // 1024 floats, shared scratch

  const int t = threadIdx.x;
  const int b0 = blockIdx.x * NB;
  const int steps = p_steps[0];
  const int mult = p_mult[0];

  const float* dW1t = ws + OFF_DW1T;
  const float* dW2t = ws + OFF_DW2T;
  const float* dW3t = ws + OFF_DW3T;
  const float* gW1t = ws + OFF_GW1T;
  const float* gW2t = ws + OFF_GW2T;
  const float* gW3t = ws + OFF_GW3T;
  const float* embT = ws + OFF_EMBT;
  const float* ro1T = ws + OFF_RO1T;
  const float* ro2T = ws + OFF_RO2T;

  if (t < TT) s_ts[t] = ts_g[t];
  __syncthreads();

  // ---- init: y0 = init_noise @ embT + emb_b ----
  {
    const int r = t >> 6;
    const int o = t & 63;
    const float* inr = init_noise + (size_t)(b0 + r) * INOISED;
    const float* wp = embT + o;
    float a = 0.f;
    #pragma unroll 8
    for (int i = 0; i < INOISED; ++i) { a = fmaf(inr[i], wp[0], a); wp += LATD; }
    a += emb_b[o];
    s_y[r][o] = a;
    s_z[r][o] = a;
  }
  __syncthreads();

  const float tval0 = s_ts[0];

  // f0 = drift(ts0, y0)   (input read from s_z == y0)
  l1_partial(t, tval0, s_z, dW1t, s_part);
  __syncthreads();
  hid_combine(t, s_part, dr_b1, s_h1, true);
  __syncthreads();
  hid_partial(t, s_h1, dW2t, s_part);
  __syncthreads();
  hid_combine(t, s_part, dr_b2, s_h2, true);
  __syncthreads();
  l3_partial(t, s_h2, dW3t, s_part);
  __syncthreads();
  l3_combine(t, s_part, dr_b3, s_f);
  // dw init: dwi = 0, dwn = dWn[0]
  if (t < 128) {
    const int half = t >> 6, r = (t >> 4) & 3, n = t & 15;
    if (half == 0) {
      s_dwi[r][n] = 0.f;
    } else {
      const float dt0 = s_ts[1] - s_ts[0];
      s_dwn[r][n] = bm[(size_t)(b0 + r) * NOISED + n] * sqrtf(dt0);
    }
  }
  __syncthreads();
  // g0 = diffusion(ts0, y0); v = g0 . dWn[0]
  l1_partial(t, tval0, s_z, gW1t, s_part);
  __syncthreads();
  hid_combine(t, s_part, di_b1, s_h1, true);
  __syncthreads();
  hid_partial(t, s_h1, gW2t, s_part);
  __syncthreads();
  hid_combine(t, s_part, di_b2, s_h2, true);
  __syncthreads();
  diff_layer3(t, s_h2, gW3t, di_b3, s_dwi, s_dwn, s_u1, s_v1);
  __syncthreads();
  {
    const int r = t >> 6;
    const int o = t & 63;
    s_v[r][o] = s_v1[r][o];
  }
  __syncthreads();
  // readout of y0 at tidx=0
  ro1_partial(t, s_y, ro1T, s_part);
  __syncthreads();
  hid_combine(t, s_part, ro_b1, s_h1, true);
  __syncthreads();
  ro2_partial(t, s_h1, ro2T, s_part);
  __syncthreads();
  ro2_final(t, s_part, ro_b2, out, b0, 0, steps, mult);
  __syncthreads();

  // ---- main time loop ----
  for (int st = 0; st < TT - 1; ++st) {
    const float t1 = s_ts[st + 1];
    const float dti = t1 - s_ts[st];
    // stage noise increments
    if (t < 128) {
      const int half = t >> 6, r = (t >> 4) & 3, n = t & 15;
      if (half == 0) {
        s_dwi[r][n] = bm[((size_t)st * NBATCH + b0 + r) * NOISED + n] * sqrtf(dti);
      } else {
        float val = 0.f;
        if (st + 1 < TT - 1) {
          const float dtn = s_ts[st + 2] - s_ts[st + 1];
          val = bm[((size_t)(st + 1) * NBATCH + b0 + r) * NOISED + n] * sqrtf(dtn);
        }
        s_dwn[r][n] = val;
      }
    }
    // z1 = 2y - z + f*dt + g_prev . dw   (v holds g_prev . dw_st)
    {
      const int r = t >> 6;
      const int o = t & 63;
      s_z[r][o] = 2.f * s_y[r][o] - s_z[r][o] + s_f[r][o] * dti + s_v[r][o];
    }
    __syncthreads();
    // drift(t1, z1) -> s_f1
    l1_partial(t, t1, s_z, dW1t, s_part);
    __syncthreads();
    hid_combine(t, s_part, dr_b1, s_h1, true);
    __syncthreads();
    hid_partial(t, s_h1, dW2t, s_part);
    __syncthreads();
    hid_combine(t, s_part, dr_b2, s_h2, true);
    __syncthreads();
    l3_partial(t, s_h2, dW3t, s_part);
    __syncthreads();
    l3_combine(t, s_part, dr_b3, s_f1);
    __syncthreads();
    // diffusion(t1, z1) -> u1 = g1.dw_st, v1 = g1.dw_{st+1}
    l1_partial(t, t1, s_z, gW1t, s_part);
    __syncthreads();
    hid_combine(t, s_part, di_b1, s_h1, true);
    __syncthreads();
    hid_partial(t, s_h1, gW2t, s_part);
    __syncthreads();
    hid_combine(t, s_part, di_b2, s_h2, true);
    __syncthreads();
    diff_layer3(t, s_h2, gW3t, di_b3, s_dwi, s_dwn, s_u1, s_v1);
    __syncthreads();
    // y1 = y + 0.5(f+f1)dt + 0.5(v+u1); rotate state
    {
      const int r = t >> 6;
      const int o = t & 63;
      const float f1v = s_f1[r][o];
      const float y1 = s_y[r][o] + 0.5f * (s_f[r][o] + f1v) * dti + 0.5f * (s_v[r][o] + s_u1[r][o]);
      s_y[r][o] = y1;
      s_f[r][o] = f1v;
      s_v[r][o] = s_v1[r][o];
    }
    __syncthreads();
    // fused readout of y1 at tidx = st+1
    ro1_partial(t, s_y, ro1T, s_part);
    __syncthreads();
    hid_combine(t, s_part, ro_b1, s_h1, true);
    __syncthreads();
    ro2_partial(t, s_h1, ro2T, s_part);
    __syncthreads();
    ro2_final(t, s_part, ro_b2, out, b0, st + 1, steps, mult);
    __syncthreads();
  }
}

extern "C" void kernel_launch(void* const* d_in, const int* in_sizes, int n_in,
                              void* d_out, int out_size, void* d_ws, size_t ws_size,
                              hipStream_t stream) {
  (void)in_sizes; (void)n_in; (void)out_size; (void)ws_size;
  const float* init_noise = (const float*)d_in[0];
  const float* bm_noise   = (const float*)d_in[1];
  const float* ts         = (const float*)d_in[2];
  const int*   p_steps    = (const int*)d_in[3];
  const int*   p_mult     = (const int*)d_in[4];
  const float* emb_W = (const float*)d_in[5];
  const float* emb_b = (const float*)d_in[6];
  const float* dr_v1 = (const float*)d_in[7];
  const float* dr_g1 = (const float*)d_in[8];
  const float* dr_b1 = (const float*)d_in[9];
  const float* dr_v2 = (const float*)d_in[10];
  const float* dr_g2 = (const float*)d_in[11];
  const float* dr_b2 = (const float*)d_in[12];
  const float* dr_v3 = (const float*)d_in[13];
  const float* dr_g3 = (const float*)d_in[14];
  const float* dr_b3 = (const float*)d_in[15];
  const float* di_v1 = (const float*)d_in[16];
  const float* di_g1 = (const float*)d_in[17];
  const float* di_b1 = (const float*)d_in[18];
  const float* di_v2 = (const float*)d_in[19];
  const float* di_g2 = (const float*)d_in[20];
  const float* di_b2 = (const float*)d_in[21];
  const float* di_v3 = (const float*)d_in[22];
  const float* di_g3 = (const float*)d_in[23];
  const float* di_b3 = (const float*)d_in[24];
  const float* ro_W1 = (const float*)d_in[25];
  const float* ro_b1 = (const float*)d_in[26];
  const float* ro_W2 = (const float*)d_in[27];
  const float* ro_b2 = (const float*)d_in[28];
  float* ws = (float*)d_ws;
  float* out = (float*)d_out;

  prep_kernel<<<dim3(1024, 9), 128, 0, stream>>>(
      dr_v1, dr_g1, dr_v2, dr_g2, dr_v3, dr_g3,
      di_v1, di_g1, di_v2, di_g2, di_v3, di_g3,
      emb_W, ro_W1, ro_W2, ws);

  sde_main<<<256, 256, 0, stream>>>(
      init_noise, bm_noise, ts, p_steps, p_mult,
      emb_b, dr_b1, dr_b2, dr_b3, di_b1, di_b2, di_b3,
      ro_b1, ro_b2, ws, out);
}

// Round 2
// 1842.424 us; speedup vs baseline: 1.3148x; 1.3148x over previous
//
#include <hip/hip_runtime.h>
#include <math.h>

#define NBATCH 1024
#define LATD 64
#define HIDD 128
#define NOISED 16
#define OUTD 32
#define INOISED 64
#define TT 128
#define NB 4   // batch rows per block

// ws layout (float offsets)
#define OFF_DW1T 0        // [65][128]
#define OFF_DW2T 8320     // [128][128]
#define OFF_DW3T 24704    // [128][64]
#define OFF_GW1T 32896    // [65][128]
#define OFF_GW2T 41216    // [128][128]
#define OFF_GW3T 57600    // [128][1024]
#define OFF_EMBT 188672   // [64][64]
#define OFF_RO1T 192768   // [64][128]
#define OFF_RO2T 200960   // [128][32]

__device__ __forceinline__ float lipswish(float x) {
  return 0.909f * x / (1.0f + expf(-x));
}

// ---------------- prep: weight-norm + transpose into ws ----------------
__global__ void prep_kernel(const float* dr_v1, const float* dr_g1,
                            const float* dr_v2, const float* dr_g2,
                            const float* dr_v3, const float* dr_g3,
                            const float* di_v1, const float* di_g1,
                            const float* di_v2, const float* di_g2,
                            const float* di_v3, const float* di_g3,
                            const float* emb_W, const float* ro_W1, const float* ro_W2,
                            float* ws) {
  __shared__ float sred[2];
  const int mat = blockIdx.y;
  const int row = blockIdx.x;
  const int i = threadIdx.x;
  const float* v = nullptr; const float* g = nullptr; float* outp = nullptr;
  int rows = 0, len = 0, ldo = 0;
  switch (mat) {
    case 0: v = dr_v1; g = dr_g1; outp = ws + OFF_DW1T; rows = 128;  len = 65;  ldo = 128;  break;
    case 1: v = dr_v2; g = dr_g2; outp = ws + OFF_DW2T; rows = 128;  len = 128; ldo = 128;  break;
    case 2: v = dr_v3; g = dr_g3; outp = ws + OFF_DW3T; rows = 64;   len = 128; ldo = 64;   break;
    case 3: v = di_v1; g = di_g1; outp = ws + OFF_GW1T; rows = 128;  len = 65;  ldo = 128;  break;
    case 4: v = di_v2; g = di_g2; outp = ws + OFF_GW2T; rows = 128;  len = 128; ldo = 128;  break;
    case 5: v = di_v3; g = di_g3; outp = ws + OFF_GW3T; rows = 1024; len = 128; ldo = 1024; break;
    case 6: v = emb_W; g = nullptr; outp = ws + OFF_EMBT; rows = 64;  len = 64;  ldo = 64;  break;
    case 7: v = ro_W1; g = nullptr; outp = ws + OFF_RO1T; rows = 128; len = 64;  ldo = 128; break;
    case 8: v = ro_W2; g = nullptr; outp = ws + OFF_RO2T; rows = 32;  len = 128; ldo = 32;  break;
  }
  if (row >= rows) return;
  const float x = (i < len) ? v[(size_t)row * len + i] : 0.0f;
  float scale = 1.0f;
  if (g != nullptr) {
    float ss = x * x;
    #pragma unroll
    for (int d = 1; d < 64; d <<= 1) ss += __shfl_xor(ss, d);
    if ((threadIdx.x & 63) == 0) sred[threadIdx.x >> 6] = ss;
    __syncthreads();
    const float tot = sred[0] + sred[1];
    scale = g[row] / sqrtf(tot);
  }
  if (i < len) outp[(size_t)i * ldo + row] = x * scale;
}

// ---------------- main persistent kernel: 512 threads, 4 rows/block ----------------
__global__ void __launch_bounds__(512, 2)
sde_main(const float* __restrict__ init_noise, const float* __restrict__ bm,
         const float* __restrict__ ts_g, const int* __restrict__ p_steps,
         const int* __restrict__ p_mult, const float* __restrict__ emb_b,
         const float* __restrict__ dr_b1, const float* __restrict__ dr_b2, const float* __restrict__ dr_b3,
         const float* __restrict__ di_b1, const float* __restrict__ di_b2, const float* __restrict__ di_b3,
         const float* __restrict__ ro_b1, const float* __restrict__ ro_b2,
         const float* __restrict__ ws, float* __restrict__ out)
{
  __shared__ __align__(16) float s_ts[TT];
  __shared__ __align__(16) float s_y[NB][LATD], s_z[NB][LATD], s_f[NB][LATD], s_v[NB][LATD];
  __shared__ __align__(16) float s_dwi[NB][NOISED], s_dwn[NB][NOISED];
  __shared__ __align__(16) float s_h1[2][NB][HIDD], s_h2[2][NB][HIDD];
  __shared__ __align__(16) float s_p[4096];            // L1/L2 partials [net][q][r][128]; aliased as s_hr[32][128]
  __shared__ __align__(16) float s_pd[4][NB][LATD];    // drift L3 partials
  __shared__ __align__(16) float s_up[2][NB][LATD], s_vp[2][NB][LATD];
  __shared__ __align__(16) float s_ub[NB][LATD], s_vb[NB][LATD];
  __shared__ __align__(16) float s_ybuf[8][NB][LATD];
  __shared__ __align__(16) float s_b1[2][HIDD], s_b2[2][HIDD], s_b3d[LATD], s_b3g[1024];
  __shared__ __align__(16) float s_rob1[HIDD], s_rob2[OUTD];

  const int t = threadIdx.x;
  const int b0 = blockIdx.x * NB;
  const int steps = p_steps[0];
  const int mult  = p_mult[0];

  const float* __restrict__ dW1t = ws + OFF_DW1T;
  const float* __restrict__ dW2t = ws + OFF_DW2T;
  const float* __restrict__ dW3t = ws + OFF_DW3T;
  const float* __restrict__ gW1t = ws + OFF_GW1T;
  const float* __restrict__ gW2t = ws + OFF_GW2T;
  const float* __restrict__ gW3t = ws + OFF_GW3T;
  const float* __restrict__ embT = ws + OFF_EMBT;
  const float* __restrict__ ro1T = ws + OFF_RO1T;
  const float* __restrict__ ro2T = ws + OFF_RO2T;

  // ---- stage constants ----
  if (t < TT) s_ts[t] = ts_g[t];
  if (t >= 128 && t < 256) { const int i = t - 128; s_b1[0][i] = dr_b1[i]; s_b1[1][i] = di_b1[i]; }
  if (t >= 256 && t < 384) { const int i = t - 256; s_b2[0][i] = dr_b2[i]; s_b2[1][i] = di_b2[i]; }
  if (t >= 384) {
    const int i = t - 384;
    s_rob1[i] = ro_b1[i];
    if (i < 64) s_b3d[i] = dr_b3[i];
    else if (i < 96) s_rob2[i - 64] = ro_b2[i - 64];
  }
  for (int i = t; i < 1024; i += 512) s_b3g[i] = di_b3[i];

  // ---- init state ----
  if (t < 256) {
    const int r = t >> 6, o = t & 63;
    const float* __restrict__ inr = init_noise + (size_t)(b0 + r) * INOISED;
    const float* __restrict__ wp = embT + o;
    float a = 0.f;
    #pragma unroll 8
    for (int i = 0; i < INOISED; ++i) { a = fmaf(inr[i], wp[0], a); wp += LATD; }
    a += emb_b[o];
    s_y[r][o] = a; s_z[r][o] = a; s_f[r][o] = 0.f; s_v[r][o] = 0.f;
  }
  if (t < 64) { const int r = t >> 4, n = t & 15; s_dwn[r][n] = 0.f; }
  __syncthreads();

  const int net = t >> 8;            // 0 = drift, 1 = diffusion
  const int q   = (t >> 6) & 3;      // K-quarter
  const int o2  = t & 63;            // output pair index
  const int col = o2 * 2;

  for (int k = 0; k < TT; ++k) {
    const float tval = s_ts[k];

    // ==== ph_L1: both nets, 65 -> 128, partials over K-quarters ====
    {
      const float* __restrict__ W = net ? gW1t : dW1t;
      float2 a0 = {0.f,0.f}, a1 = {0.f,0.f}, a2 = {0.f,0.f}, a3 = {0.f,0.f};
      if (q == 0) {
        const float2 w = *(const float2*)&W[col];
        a0.x = w.x * tval; a0.y = w.y * tval; a1 = a0; a2 = a0; a3 = a0;
      }
      const int i0 = q * 16;
      const float* __restrict__ Wr = W + (size_t)(1 + i0) * HIDD + col;
      #pragma unroll
      for (int i4 = 0; i4 < 4; ++i4) {
        const float4 z0 = *(const float4*)&s_z[0][i0 + i4*4];
        const float4 z1 = *(const float4*)&s_z[1][i0 + i4*4];
        const float4 z2 = *(const float4*)&s_z[2][i0 + i4*4];
        const float4 z3 = *(const float4*)&s_z[3][i0 + i4*4];
        const float za[4] = {z0.x, z0.y, z0.z, z0.w};
        const float zb[4] = {z1.x, z1.y, z1.z, z1.w};
        const float zc[4] = {z2.x, z2.y, z2.z, z2.w};
        const float zd[4] = {z3.x, z3.y, z3.z, z3.w};
        #pragma unroll
        for (int j = 0; j < 4; ++j) {
          const float2 w = *(const float2*)&Wr[(size_t)(i4*4 + j) * HIDD];
          a0.x = fmaf(za[j], w.x, a0.x); a0.y = fmaf(za[j], w.y, a0.y);
          a1.x = fmaf(zb[j], w.x, a1.x); a1.y = fmaf(zb[j], w.y, a1.y);
          a2.x = fmaf(zc[j], w.x, a2.x); a2.y = fmaf(zc[j], w.y, a2.y);
          a3.x = fmaf(zd[j], w.x, a3.x); a3.y = fmaf(zd[j], w.y, a3.y);
        }
      }
      float* pb = s_p + (size_t)((net*4 + q)*4) * HIDD + col;
      *(float2*)&pb[0*HIDD] = a0; *(float2*)&pb[1*HIDD] = a1;
      *(float2*)&pb[2*HIDD] = a2; *(float2*)&pb[3*HIDD] = a3;
    }
    __syncthreads();

    // ==== ph_c1: combine + lipswish -> s_h1; also rotate noise increments ====
    {
      const int rn = (t >> 6) & 3;
      float2 x = { s_b1[net][col], s_b1[net][col+1] };
      #pragma unroll
      for (int qq = 0; qq < 4; ++qq) {
        const float2 pv = *(const float2*)&s_p[(size_t)((net*4 + qq)*4 + rn) * HIDD + col];
        x.x += pv.x; x.y += pv.y;
      }
      s_h1[net][rn][col]   = lipswish(x.x);
      s_h1[net][rn][col+1] = lipswish(x.y);
      if (t < 64) {  // dwi_k = dw_{k-1} (old dwn); dwn_k = dw_k
        const int r = t >> 4, n = t & 15;
        const float tmp = s_dwn[r][n];
        float nv = 0.f;
        if (k < TT - 1) nv = bm[((size_t)k * NBATCH + b0 + r) * NOISED + n] * sqrtf(s_ts[k+1] - s_ts[k]);
        s_dwn[r][n] = nv;
        s_dwi[r][n] = tmp;
      }
    }
    __syncthreads();

    // ==== ph_L2: both nets, 128 -> 128, partials over K-quarters ====
    {
      const float* __restrict__ W = net ? gW2t : dW2t;
      const int i0 = q * 32;
      float2 a0 = {0.f,0.f}, a1 = {0.f,0.f}, a2 = {0.f,0.f}, a3 = {0.f,0.f};
      const float* __restrict__ Wr = W + (size_t)i0 * HIDD + col;
      #pragma unroll
      for (int i4 = 0; i4 < 8; ++i4) {
        const float4 h0 = *(const float4*)&s_h1[net][0][i0 + i4*4];
        const float4 h1 = *(const float4*)&s_h1[net][1][i0 + i4*4];
        const float4 h2 = *(const float4*)&s_h1[net][2][i0 + i4*4];
        const float4 h3 = *(const float4*)&s_h1[net][3][i0 + i4*4];
        const float ha[4] = {h0.x, h0.y, h0.z, h0.w};
        const float hb[4] = {h1.x, h1.y, h1.z, h1.w};
        const float hc[4] = {h2.x, h2.y, h2.z, h2.w};
        const float hd[4] = {h3.x, h3.y, h3.z, h3.w};
        #pragma unroll
        for (int j = 0; j < 4; ++j) {
          const float2 w = *(const float2*)&Wr[(size_t)(i4*4 + j) * HIDD];
          a0.x = fmaf(ha[j], w.x, a0.x); a0.y = fmaf(ha[j], w.y, a0.y);
          a1.x = fmaf(hb[j], w.x, a1.x); a1.y = fmaf(hb[j], w.y, a1.y);
          a2.x = fmaf(hc[j], w.x, a2.x); a2.y = fmaf(hc[j], w.y, a2.y);
          a3.x = fmaf(hd[j], w.x, a3.x); a3.y = fmaf(hd[j], w.y, a3.y);
        }
      }
      float* pb = s_p + (size_t)((net*4 + q)*4) * HIDD + col;
      *(float2*)&pb[0*HIDD] = a0; *(float2*)&pb[1*HIDD] = a1;
      *(float2*)&pb[2*HIDD] = a2; *(float2*)&pb[3*HIDD] = a3;
    }
    __syncthreads();

    // ==== ph_c2: combine + lipswish -> s_h2 ====
    {
      const int rn = (t >> 6) & 3;
      float2 x = { s_b2[net][col], s_b2[net][col+1] };
      #pragma unroll
      for (int qq = 0; qq < 4; ++qq) {
        const float2 pv = *(const float2*)&s_p[(size_t)((net*4 + qq)*4 + rn) * HIDD + col];
        x.x += pv.x; x.y += pv.y;
      }
      s_h2[net][rn][col]   = lipswish(x.x);
      s_h2[net][rn][col+1] = lipswish(x.y);
    }
    __syncthreads();

    // ==== ph_L3g: diffusion 128 -> 1024 fused with dual noise contraction ====
    {
      const int ih = t >> 8, o4 = t & 255;
      const int c4 = o4 * 4, i0 = ih * 64;
      float4 ac0 = {0,0,0,0}, ac1 = {0,0,0,0}, ac2 = {0,0,0,0}, ac3 = {0,0,0,0};
      const float* __restrict__ Wg = gW3t + (size_t)i0 * NBATCH + c4;
      #pragma unroll 4
      for (int i4 = 0; i4 < 16; ++i4) {
        const float4 h0 = *(const float4*)&s_h2[1][0][i0 + i4*4];
        const float4 h1 = *(const float4*)&s_h2[1][1][i0 + i4*4];
        const float4 h2 = *(const float4*)&s_h2[1][2][i0 + i4*4];
        const float4 h3 = *(const float4*)&s_h2[1][3][i0 + i4*4];
        const float ha[4] = {h0.x, h0.y, h0.z, h0.w};
        const float hb[4] = {h1.x, h1.y, h1.z, h1.w};
        const float hc[4] = {h2.x, h2.y, h2.z, h2.w};
        const float hd[4] = {h3.x, h3.y, h3.z, h3.w};
        #pragma unroll
        for (int j = 0; j < 4; ++j) {
          const float4 w = *(const float4*)&Wg[(size_t)(i4*4 + j) * NBATCH];
          ac0.x = fmaf(ha[j], w.x, ac0.x); ac0.y = fmaf(ha[j], w.y, ac0.y);
          ac0.z = fmaf(ha[j], w.z, ac0.z); ac0.w = fmaf(ha[j], w.w, ac0.w);
          ac1.x = fmaf(hb[j], w.x, ac1.x); ac1.y = fmaf(hb[j], w.y, ac1.y);
          ac1.z = fmaf(hb[j], w.z, ac1.z); ac1.w = fmaf(hb[j], w.w, ac1.w);
          ac2.x = fmaf(hc[j], w.x, ac2.x); ac2.y = fmaf(hc[j], w.y, ac2.y);
          ac2.z = fmaf(hc[j], w.z, ac2.z); ac2.w = fmaf(hc[j], w.w, ac2.w);
          ac3.x = fmaf(hd[j], w.x, ac3.x); ac3.y = fmaf(hd[j], w.y, ac3.y);
          ac3.z = fmaf(hd[j], w.z, ac3.z); ac3.w = fmaf(hd[j], w.w, ac3.w);
        }
      }
      const int l = o4 >> 2, n0 = (o4 & 3) * 4;
      float uu[4], vv[4];
      {
        const float4 a[4] = {ac0, ac1, ac2, ac3};
        #pragma unroll
        for (int r = 0; r < 4; ++r) {
          const float4 di = *(const float4*)&s_dwi[r][n0];
          const float4 dn = *(const float4*)&s_dwn[r][n0];
          uu[r] = a[r].x*di.x + a[r].y*di.y + a[r].z*di.z + a[r].w*di.w;
          vv[r] = a[r].x*dn.x + a[r].y*dn.y + a[r].z*dn.z + a[r].w*dn.w;
        }
      }
      #pragma unroll
      for (int r = 0; r < 4; ++r) {
        uu[r] += __shfl_xor(uu[r], 1); uu[r] += __shfl_xor(uu[r], 2);
        vv[r] += __shfl_xor(vv[r], 1); vv[r] += __shfl_xor(vv[r], 2);
      }
      if ((o4 & 3) == 0) {
        #pragma unroll
        for (int r = 0; r < 4; ++r) { s_up[ih][r][l] = uu[r]; s_vp[ih][r][l] = vv[r]; }
      }
    }
    __syncthreads();

    // ==== phD: drift 128 -> 64 partials; other half: b3 noise-dot ====
    if (t < 256) {
      const int qd = t >> 6, o = t & 63;
      const int i0 = qd * 32;
      float a0 = 0.f, a1 = 0.f, a2 = 0.f, a3 = 0.f;
      const float* __restrict__ Wd = dW3t + (size_t)i0 * LATD + o;
      #pragma unroll
      for (int i4 = 0; i4 < 8; ++i4) {
        const float4 h0 = *(const float4*)&s_h2[0][0][i0 + i4*4];
        const float4 h1 = *(const float4*)&s_h2[0][1][i0 + i4*4];
        const float4 h2 = *(const float4*)&s_h2[0][2][i0 + i4*4];
        const float4 h3 = *(const float4*)&s_h2[0][3][i0 + i4*4];
        const float ha[4] = {h0.x, h0.y, h0.z, h0.w};
        const float hb[4] = {h1.x, h1.y, h1.z, h1.w};
        const float hc[4] = {h2.x, h2.y, h2.z, h2.w};
        const float hd[4] = {h3.x, h3.y, h3.z, h3.w};
        #pragma unroll
        for (int j = 0; j < 4; ++j) {
          const float w = Wd[(size_t)(i4*4 + j) * LATD];
          a0 = fmaf(ha[j], w, a0); a1 = fmaf(hb[j], w, a1);
          a2 = fmaf(hc[j], w, a2); a3 = fmaf(hd[j], w, a3);
        }
      }
      s_pd[qd][0][o] = a0; s_pd[qd][1][o] = a1; s_pd[qd][2][o] = a2; s_pd[qd][3][o] = a3;
    } else {
      const int tt2 = t - 256;
      const int r = tt2 >> 6, l = tt2 & 63;
      float ub = 0.f, vb = 0.f;
      #pragma unroll
      for (int j = 0; j < 4; ++j) {
        const float4 b4  = *(const float4*)&s_b3g[l*16 + j*4];
        const float4 di4 = *(const float4*)&s_dwi[r][j*4];
        const float4 dn4 = *(const float4*)&s_dwn[r][j*4];
        ub += b4.x*di4.x + b4.y*di4.y + b4.z*di4.z + b4.w*di4.w;
        vb += b4.x*dn4.x + b4.y*dn4.y + b4.z*dn4.z + b4.w*dn4.w;
      }
      s_ub[r][l] = ub; s_vb[r][l] = vb;
    }
    __syncthreads();

    // ==== upd: f1 combine, u1/v1, Heun update, rotate state ====
    if (t < 256) {
      const int r = t >> 6, o = t & 63;
      const float f1 = s_pd[0][r][o] + s_pd[1][r][o] + s_pd[2][r][o] + s_pd[3][r][o] + s_b3d[o];
      const float u1 = s_up[0][r][o] + s_up[1][r][o] + s_ub[r][o];
      const float v1 = s_vp[0][r][o] + s_vp[1][r][o] + s_vb[r][o];
      const float dti = (k > 0) ? (s_ts[k] - s_ts[k-1]) : 0.f;
      const float dtn = (k < TT-1) ? (s_ts[k+1] - s_ts[k]) : 0.f;
      const float y1 = s_y[r][o] + 0.5f*(s_f[r][o] + f1)*dti + 0.5f*(s_v[r][o] + u1);
      const float z1 = 2.f*y1 - s_z[r][o] + f1*dtn + v1;
      s_y[r][o] = y1; s_z[r][o] = z1; s_f[r][o] = f1; s_v[r][o] = v1;
      s_ybuf[k & 7][r][o] = y1;
    }
    __syncthreads();

    // ==== batched readout every 8 steps: 32 tokens through 64->128->32 ====
    if ((k & 7) == 7) {
      {
        const int oo = t & 127, tq = t >> 7;
        float acc[8];
        #pragma unroll
        for (int j = 0; j < 8; ++j) acc[j] = s_rob1[oo];
        const float* __restrict__ Wr = ro1T + oo;
        #pragma unroll 4
        for (int i4 = 0; i4 < 16; ++i4) {
          float w4[4];
          #pragma unroll
          for (int j = 0; j < 4; ++j) w4[j] = Wr[(size_t)(i4*4 + j) * HIDD];
          #pragma unroll
          for (int jt = 0; jt < 8; ++jt) {
            const int tok = tq*8 + jt;
            const float4 y4 = *(const float4*)&s_ybuf[tok >> 2][tok & 3][i4*4];
            acc[jt] = fmaf(y4.x, w4[0], acc[jt]);
            acc[jt] = fmaf(y4.y, w4[1], acc[jt]);
            acc[jt] = fmaf(y4.z, w4[2], acc[jt]);
            acc[jt] = fmaf(y4.w, w4[3], acc[jt]);
          }
        }
        #pragma unroll
        for (int jt = 0; jt < 8; ++jt) {
          const int tok = tq*8 + jt;
          s_p[(size_t)tok * HIDD + oo] = lipswish(acc[jt]);
        }
      }
      __syncthreads();
      {
        const int o = t & 31, gg = t >> 5;
        float a0 = s_rob2[o], a1 = s_rob2[o];
        const float* __restrict__ Wr = ro2T + o;
        const float* __restrict__ h0 = s_p + (size_t)(gg*2) * HIDD;
        const float* __restrict__ h1 = h0 + HIDD;
        #pragma unroll 4
        for (int i4 = 0; i4 < 32; ++i4) {
          const float4 hx = *(const float4*)&h0[i4*4];
          const float4 hy = *(const float4*)&h1[i4*4];
          const float hxa[4] = {hx.x, hx.y, hx.z, hx.w};
          const float hya[4] = {hy.x, hy.y, hy.z, hy.w};
          #pragma unroll
          for (int j = 0; j < 4; ++j) {
            const float w = Wr[(size_t)(i4*4 + j) * OUTD];
            a0 = fmaf(hxa[j], w, a0);
            a1 = fmaf(hya[j], w, a1);
          }
        }
        #pragma unroll
        for (int u2 = 0; u2 < 2; ++u2) {
          const int tok = gg*2 + u2;
          const int kk = tok >> 2, r = tok & 3;
          const int tg = k - 7 + kk;
          const float val = u2 ? a1 : a0;
          out[((size_t)(b0 + r) * TT + tg) * OUTD + o] = val;
          if (mult > 0 && (tg % mult) == 0) {
            const int jj = tg / mult;
            if (jj < steps)
              out[(size_t)NBATCH * TT * OUTD + ((size_t)(b0 + r) * steps + jj) * OUTD + o] = val;
          }
        }
      }
      __syncthreads();
    }
  }
}

extern "C" void kernel_launch(void* const* d_in, const int* in_sizes, int n_in,
                              void* d_out, int out_size, void* d_ws, size_t ws_size,
                              hipStream_t stream) {
  (void)in_sizes; (void)n_in; (void)out_size; (void)ws_size;
  const float* init_noise = (const float*)d_in[0];
  const float* bm_noise   = (const float*)d_in[1];
  const float* ts         = (const float*)d_in[2];
  const int*   p_steps    = (const int*)d_in[3];
  const int*   p_mult     = (const int*)d_in[4];
  const float* emb_W = (const float*)d_in[5];
  const float* emb_b = (const float*)d_in[6];
  const float* dr_v1 = (const float*)d_in[7];
  const float* dr_g1 = (const float*)d_in[8];
  const float* dr_b1 = (const float*)d_in[9];
  const float* dr_v2 = (const float*)d_in[10];
  const float* dr_g2 = (const float*)d_in[11];
  const float* dr_b2 = (const float*)d_in[12];
  const float* dr_v3 = (const float*)d_in[13];
  const float* dr_g3 = (const float*)d_in[14];
  const float* dr_b3 = (const float*)d_in[15];
  const float* di_v1 = (const float*)d_in[16];
  const float* di_g1 = (const float*)d_in[17];
  const float* di_b1 = (const float*)d_in[18];
  const float* di_v2 = (const float*)d_in[19];
  const float* di_g2 = (const float*)d_in[20];
  const float* di_b2 = (const float*)d_in[21];
  const float* di_v3 = (const float*)d_in[22];
  const float* di_g3 = (const float*)d_in[23];
  const float* di_b3 = (const float*)d_in[24];
  const float* ro_W1 = (const float*)d_in[25];
  const float* ro_b1 = (const float*)d_in[26];
  const float* ro_W2 = (const float*)d_in[27];
  const float* ro_b2 = (const float*)d_in[28];
  float* ws = (float*)d_ws;
  float* out = (float*)d_out;

  prep_kernel<<<dim3(1024, 9), 128, 0, stream>>>(
      dr_v1, dr_g1, dr_v2, dr_g2, dr_v3, dr_g3,
      di_v1, di_g1, di_v2, di_g2, di_v3, di_g3,
      emb_W, ro_W1, ro_W2, ws);

  sde_main<<<256, 512, 0, stream>>>(
      init_noise, bm_noise, ts, p_steps, p_mult,
      emb_b, dr_b1, dr_b2, dr_b3, di_b1, di_b2, di_b3,
      ro_b1, ro_b2, ws, out);
}